// Round 2
// baseline (1252.804 us; speedup 1.0000x reference)
//
#include <hip/hip_runtime.h>
#include <hip/hip_bf16.h>
#include <math.h>

#define H 2048
#define IMOE 1408
#define NEXP 8
#define T_TOK 2048
#define ISH 2816
#define SCALEF 2.5f

typedef __attribute__((ext_vector_type(8))) short short8;
typedef __attribute__((ext_vector_type(4))) short short4v;
typedef __attribute__((ext_vector_type(4))) float floatx4;

#define LDS_STRIDE 72  // 64 + 8 pad (shorts): row stride 144B -> 2-way bank alias (free)

__device__ inline float b2f(short v) {
    unsigned int u = ((unsigned int)(unsigned short)v) << 16;
    float f; __builtin_memcpy(&f, &u, 4); return f;
}
__device__ inline short f2b(float f) {
    __hip_bfloat16 h = __float2bfloat16(f);
    short s; __builtin_memcpy(&s, &h, 2); return s;
}

// ---------------- Router (fp32, matches reference exactly) ----------------
__global__ __launch_bounds__(256) void router_kernel(
    const float* __restrict__ x, const float* __restrict__ rw,
    const float* __restrict__ bias,
    int* __restrict__ cnt, int* __restrict__ tokList, int* __restrict__ slotList,
    float* __restrict__ pairW)
{
    const int wid  = (blockIdx.x * 256 + threadIdx.x) >> 6;  // token
    const int lane = threadIdx.x & 63;
    if (wid >= T_TOK) return;
    const float* xr = x + (size_t)wid * H;

    float acc[NEXP];
#pragma unroll
    for (int e = 0; e < NEXP; ++e) acc[e] = 0.f;

    // H = 2048 = 64 lanes * 8 float4
#pragma unroll
    for (int c = 0; c < 8; ++c) {
        int idx = (c * 64 + lane) * 4;
        floatx4 xv = *(const floatx4*)(xr + idx);
#pragma unroll
        for (int e = 0; e < NEXP; ++e) {
            floatx4 wv = *(const floatx4*)(rw + e * H + idx);
            acc[e] += xv.x * wv.x + xv.y * wv.y + xv.z * wv.z + xv.w * wv.w;
        }
    }
#pragma unroll
    for (int e = 0; e < NEXP; ++e)
        for (int off = 32; off; off >>= 1)
            acc[e] += __shfl_xor(acc[e], off, 64);

    if (lane == 0) {
        float s[NEXP], sfc[NEXP];
#pragma unroll
        for (int e = 0; e < NEXP; ++e) {
            s[e]   = 1.0f / (1.0f + expf(-acc[e]));
            sfc[e] = s[e] + bias[e];
        }
        float gs[4];
#pragma unroll
        for (int g = 0; g < 4; ++g) gs[g] = sfc[2 * g] + sfc[2 * g + 1];
        int g1 = 0;
        for (int g = 1; g < 4; ++g) if (gs[g] > gs[g1]) g1 = g;
        int g2 = -1;
        for (int g = 0; g < 4; ++g) {
            if (g == g1) continue;
            if (g2 < 0 || gs[g] > gs[g2]) g2 = g;
        }
        float msk[NEXP];
#pragma unroll
        for (int e = 0; e < NEXP; ++e) {
            int g = e >> 1;
            msk[e] = (g == g1 || g == g2) ? sfc[e] : 0.0f;
        }
        int e1 = 0;
        for (int e = 1; e < NEXP; ++e) if (msk[e] > msk[e1]) e1 = e;
        int e2 = -1;
        for (int e = 0; e < NEXP; ++e) {
            if (e == e1) continue;
            if (e2 < 0 || msk[e] > msk[e2]) e2 = e;
        }
        float w1 = s[e1], w2 = s[e2];
        float inv = SCALEF / (w1 + w2 + 1e-20f);
        w1 *= inv; w2 *= inv;
        int p1 = atomicAdd(&cnt[e1], 1);
        tokList[e1 * T_TOK + p1]  = wid;
        slotList[e1 * T_TOK + p1] = 2 * wid;
        pairW[2 * wid] = w1;
        int p2 = atomicAdd(&cnt[e2], 1);
        tokList[e2 * T_TOK + p2]  = wid;
        slotList[e2 * T_TOK + p2] = 2 * wid + 1;
        pairW[2 * wid + 1] = w2;
    }
}

// ---------------- Grouped GEMM ----------------
// C[m][n] = sum_k A[gather[m]][k] * B[n][k]   (B fp32, stored [N][K] K-major)
// A is fp32 (A_BF16=false, gate/up from x) or bf16 (A_BF16=true, down from hidden).
// fp32 -> bf16 conversion happens during LDS staging; MFMA in bf16, fp32 accum.
// GATEUP: two B matrices, epilogue silu(g)*u, bf16 C. DOWN: single B, bf16 C.
template <bool GATEUP, bool A_BF16>
__global__ __launch_bounds__(256) void gemm_tile(
    const void* __restrict__ Av, const float* __restrict__ B1,
    const float* __restrict__ B2, short* __restrict__ C,
    const int* __restrict__ counts, int fixedM,
    const int* __restrict__ gatherIdx, const int* __restrict__ scatterIdx,
    int N, int K)
{
    const int e = blockIdx.z;
    const int M = counts ? counts[e] : fixedM;
    const int m_base = blockIdx.y * 64;
    if (m_base >= M) return;
    const int n_base = blockIdx.x * 64;

    extern __shared__ short lds[];
    short* As  = lds;                       // [64][72]
    short* Bs1 = lds + 64 * LDS_STRIDE;
    short* Bs2 = GATEUP ? (lds + 2 * 64 * LDS_STRIDE) : nullptr;

    const float* B1e = B1 + (size_t)e * N * K;
    const float* B2e = GATEUP ? (B2 + (size_t)e * N * K) : nullptr;

    const int tid  = threadIdx.x;
    const int wave = tid >> 6;
    const int lane = tid & 63;
    const int quad = lane >> 4;
    const int l16  = lane & 15;

    // A gather rows for staging
    int asrc[4];
    if (A_BF16) {
        // 2 chunks of short8: rows (tid>>3) + 32*i
#pragma unroll
        for (int i = 0; i < 2; ++i) {
            int r = (tid >> 3) + 32 * i;
            int gr = m_base + r;
            int pos = gr < M ? gr : (M - 1);
            asrc[i] = gatherIdx ? gatherIdx[e * T_TOK + pos] : pos;
        }
    } else {
        // 4 chunks of float4: rows (tid>>4) + 16*i
#pragma unroll
        for (int i = 0; i < 4; ++i) {
            int r = (tid >> 4) + 16 * i;
            int gr = m_base + r;
            int pos = gr < M ? gr : (M - 1);
            asrc[i] = gatherIdx ? gatherIdx[e * T_TOK + pos] : pos;
        }
    }

    floatx4 accg[4] = {};
    floatx4 accu[4] = {};

    const int kIters = K >> 6;
    for (int kt = 0; kt < kIters; ++kt) {
        const int k0 = kt << 6;
        // --- stage A ---
        if (A_BF16) {
            const short* A = (const short*)Av;
#pragma unroll
            for (int i = 0; i < 2; ++i) {
                int r = (tid >> 3) + 32 * i;
                int kc = tid & 7;
                short8 av = *(const short8*)(A + (size_t)asrc[i] * K + k0 + kc * 8);
                *(short8*)(As + r * LDS_STRIDE + kc * 8) = av;
            }
        } else {
            const float* A = (const float*)Av;
#pragma unroll
            for (int i = 0; i < 4; ++i) {
                int r = (tid >> 4) + 16 * i;
                int kc = tid & 15;
                floatx4 av = *(const floatx4*)(A + (size_t)asrc[i] * K + k0 + kc * 4);
                short4v cv = { f2b(av.x), f2b(av.y), f2b(av.z), f2b(av.w) };
                *(short4v*)(As + r * LDS_STRIDE + kc * 4) = cv;
            }
        }
        // --- stage B (fp32 -> bf16) ---
#pragma unroll
        for (int i = 0; i < 4; ++i) {
            int r = (tid >> 4) + 16 * i;
            int kc = tid & 15;
            size_t goff = (size_t)(n_base + r) * K + k0 + kc * 4;
            floatx4 b1 = *(const floatx4*)(B1e + goff);
            short4v c1 = { f2b(b1.x), f2b(b1.y), f2b(b1.z), f2b(b1.w) };
            *(short4v*)(Bs1 + r * LDS_STRIDE + kc * 4) = c1;
            if (GATEUP) {
                floatx4 b2 = *(const floatx4*)(B2e + goff);
                short4v c2 = { f2b(b2.x), f2b(b2.y), f2b(b2.z), f2b(b2.w) };
                *(short4v*)(Bs2 + r * LDS_STRIDE + kc * 4) = c2;
            }
        }
        __syncthreads();
#pragma unroll
        for (int kk = 0; kk < 64; kk += 32) {
            short8 af = *(const short8*)(As + (wave * 16 + l16) * LDS_STRIDE + kk + quad * 8);
#pragma unroll
            for (int n = 0; n < 4; ++n) {
                short8 b1 = *(const short8*)(Bs1 + (n * 16 + l16) * LDS_STRIDE + kk + quad * 8);
                accg[n] = __builtin_amdgcn_mfma_f32_16x16x32_bf16(af, b1, accg[n], 0, 0, 0);
                if (GATEUP) {
                    short8 b2 = *(const short8*)(Bs2 + (n * 16 + l16) * LDS_STRIDE + kk + quad * 8);
                    accu[n] = __builtin_amdgcn_mfma_f32_16x16x32_bf16(af, b2, accu[n], 0, 0, 0);
                }
            }
        }
        __syncthreads();
    }

    // epilogue: C/D layout col=lane&15, row=quad*4+reg
#pragma unroll
    for (int n = 0; n < 4; ++n) {
#pragma unroll
        for (int r = 0; r < 4; ++r) {
            int trow = wave * 16 + quad * 4 + r;
            int grow = m_base + trow;
            if (grow >= M) continue;
            int crow = scatterIdx ? scatterIdx[e * T_TOK + grow] : grow;
            float v;
            if (GATEUP) {
                float g = accg[n][r];
                float u = accu[n][r];
                float sg = g / (1.0f + __expf(-g));
                v = sg * u;
            } else {
                v = accg[n][r];
            }
            C[(size_t)crow * N + n_base + n * 16 + l16] = f2b(v);
        }
    }
}

// ---------------- Combine (bf16 intermediates -> fp32 out) ----------------
__global__ __launch_bounds__(256) void combine_kernel(
    const short* __restrict__ outPairs, const short* __restrict__ sharedOut,
    const float* __restrict__ pairW, float* __restrict__ out)
{
    size_t gi = ((size_t)blockIdx.x * 256 + threadIdx.x) * 8;
    int t = (int)(gi >> 11);
    int h = (int)(gi & (H - 1));
    float w0 = pairW[2 * t], w1 = pairW[2 * t + 1];
    short8 p0 = *(const short8*)(outPairs + (size_t)(2 * t) * H + h);
    short8 p1 = *(const short8*)(outPairs + (size_t)(2 * t + 1) * H + h);
    short8 sh = *(const short8*)(sharedOut + gi);
    floatx4 o0, o1;
#pragma unroll
    for (int j = 0; j < 4; ++j)
        o0[j] = w0 * b2f(p0[j]) + w1 * b2f(p1[j]) + b2f(sh[j]);
#pragma unroll
    for (int j = 0; j < 4; ++j)
        o1[j] = w0 * b2f(p0[4 + j]) + w1 * b2f(p1[4 + j]) + b2f(sh[4 + j]);
    *(floatx4*)(out + gi)     = o0;
    *(floatx4*)(out + gi + 4) = o1;
}

extern "C" void kernel_launch(void* const* d_in, const int* in_sizes, int n_in,
                              void* d_out, int out_size, void* d_ws, size_t ws_size,
                              hipStream_t stream)
{
    const float* x    = (const float*)d_in[0];
    const float* rw   = (const float*)d_in[1];
    const float* bias = (const float*)d_in[2];
    const float* gw   = (const float*)d_in[3];
    const float* uw   = (const float*)d_in[4];
    const float* dw   = (const float*)d_in[5];
    const float* sgw  = (const float*)d_in[6];
    const float* suw  = (const float*)d_in[7];
    const float* sdw  = (const float*)d_in[8];
    float* out = (float*)d_out;

    char* ws = (char*)d_ws;
    size_t off = 0;
    auto alloc = [&](size_t bytes) {
        off = (off + 255) & ~(size_t)255;
        void* p = ws + off;
        off += bytes;
        return p;
    };
    int*   cnt       = (int*)  alloc(NEXP * sizeof(int));
    int*   tokList   = (int*)  alloc((size_t)NEXP * T_TOK * sizeof(int));
    int*   slotList  = (int*)  alloc((size_t)NEXP * T_TOK * sizeof(int));
    float* pairW     = (float*)alloc((size_t)2 * T_TOK * sizeof(float));
    short* hiddenP   = (short*)alloc((size_t)2 * T_TOK * IMOE * sizeof(short));
    short* outPairs  = (short*)alloc((size_t)2 * T_TOK * H * sizeof(short));
    short* hiddenS   = (short*)alloc((size_t)T_TOK * ISH * sizeof(short));
    short* sharedOut = (short*)alloc((size_t)T_TOK * H * sizeof(short));

    hipMemsetAsync(cnt, 0, NEXP * sizeof(int), stream);

    router_kernel<<<T_TOK / 4, 256, 0, stream>>>(x, rw, bias, cnt, tokList, slotList, pairW);

    const int ldsGU = 3 * 64 * LDS_STRIDE * sizeof(short);
    const int ldsDN = 2 * 64 * LDS_STRIDE * sizeof(short);

    // routed gate/up -> hiddenP[slot]
    dim3 g1(IMOE / 64, T_TOK / 64, NEXP);
    gemm_tile<true, false><<<g1, 256, ldsGU, stream>>>(x, gw, uw, hiddenP, cnt, 0,
                                                       tokList, slotList, IMOE, H);
    // routed down -> outPairs[slot]
    dim3 g2(H / 64, T_TOK / 64, NEXP);
    gemm_tile<false, true><<<g2, 256, ldsDN, stream>>>(hiddenP, dw, nullptr, outPairs, cnt, 0,
                                                       slotList, slotList, H, IMOE);
    // shared gate/up -> hiddenS
    dim3 g3(ISH / 64, T_TOK / 64, 1);
    gemm_tile<true, false><<<g3, 256, ldsGU, stream>>>(x, sgw, suw, hiddenS, nullptr, T_TOK,
                                                       nullptr, nullptr, ISH, H);
    // shared down -> sharedOut
    dim3 g4(H / 64, T_TOK / 64, 1);
    gemm_tile<false, true><<<g4, 256, ldsDN, stream>>>(hiddenS, sdw, nullptr, sharedOut, nullptr, T_TOK,
                                                       nullptr, nullptr, H, ISH);

    combine_kernel<<<(T_TOK * H / 8) / 256, 256, 0, stream>>>(outPairs, sharedOut, pairW, out);
}

// Round 3
// 1009.595 us; speedup vs baseline: 1.2409x; 1.2409x over previous
//
#include <hip/hip_runtime.h>
#include <hip/hip_bf16.h>
#include <math.h>

#define H 2048
#define IMOE 1408
#define NEXP 8
#define T_TOK 2048
#define ISH 2816
#define SCALEF 2.5f

typedef __attribute__((ext_vector_type(8))) short short8;
typedef __attribute__((ext_vector_type(4))) short short4v;
typedef __attribute__((ext_vector_type(4))) float floatx4;

__device__ inline float b2f(short v) {
    unsigned int u = ((unsigned int)(unsigned short)v) << 16;
    float f; __builtin_memcpy(&f, &u, 4); return f;
}
__device__ inline short f2b(float f) {
    __hip_bfloat16 h = __float2bfloat16(f);
    short s; __builtin_memcpy(&s, &h, 2); return s;
}

// async 16B/lane global->LDS; LDS dest = wave-uniform base + lane*16 (no padding!)
__device__ __forceinline__ void async16(const short* g, short* l) {
    __builtin_amdgcn_global_load_lds(
        (const __attribute__((address_space(1))) unsigned*)g,
        (__attribute__((address_space(3))) unsigned*)l, 16, 0, 0);
}

// ---------------- Router (fp32, matches reference exactly) ----------------
__global__ __launch_bounds__(256) void router_kernel(
    const float* __restrict__ x, const float* __restrict__ rw,
    const float* __restrict__ bias,
    int* __restrict__ cnt, int* __restrict__ tokList, int* __restrict__ slotList,
    float* __restrict__ pairW)
{
    const int wid  = (blockIdx.x * 256 + threadIdx.x) >> 6;  // token
    const int lane = threadIdx.x & 63;
    if (wid >= T_TOK) return;
    const float* xr = x + (size_t)wid * H;

    float acc[NEXP];
#pragma unroll
    for (int e = 0; e < NEXP; ++e) acc[e] = 0.f;

#pragma unroll
    for (int c = 0; c < 8; ++c) {
        int idx = (c * 64 + lane) * 4;
        floatx4 xv = *(const floatx4*)(xr + idx);
#pragma unroll
        for (int e = 0; e < NEXP; ++e) {
            floatx4 wv = *(const floatx4*)(rw + e * H + idx);
            acc[e] += xv.x * wv.x + xv.y * wv.y + xv.z * wv.z + xv.w * wv.w;
        }
    }
#pragma unroll
    for (int e = 0; e < NEXP; ++e)
        for (int off = 32; off; off >>= 1)
            acc[e] += __shfl_xor(acc[e], off, 64);

    if (lane == 0) {
        float s[NEXP], sfc[NEXP];
#pragma unroll
        for (int e = 0; e < NEXP; ++e) {
            s[e]   = 1.0f / (1.0f + expf(-acc[e]));
            sfc[e] = s[e] + bias[e];
        }
        float gs[4];
#pragma unroll
        for (int g = 0; g < 4; ++g) gs[g] = sfc[2 * g] + sfc[2 * g + 1];
        int g1 = 0;
        for (int g = 1; g < 4; ++g) if (gs[g] > gs[g1]) g1 = g;
        int g2 = -1;
        for (int g = 0; g < 4; ++g) {
            if (g == g1) continue;
            if (g2 < 0 || gs[g] > gs[g2]) g2 = g;
        }
        float msk[NEXP];
#pragma unroll
        for (int e = 0; e < NEXP; ++e) {
            int g = e >> 1;
            msk[e] = (g == g1 || g == g2) ? sfc[e] : 0.0f;
        }
        int e1 = 0;
        for (int e = 1; e < NEXP; ++e) if (msk[e] > msk[e1]) e1 = e;
        int e2 = -1;
        for (int e = 0; e < NEXP; ++e) {
            if (e == e1) continue;
            if (e2 < 0 || msk[e] > msk[e2]) e2 = e;
        }
        float w1 = s[e1], w2 = s[e2];
        float inv = SCALEF / (w1 + w2 + 1e-20f);
        w1 *= inv; w2 *= inv;
        int p1 = atomicAdd(&cnt[e1], 1);
        tokList[e1 * T_TOK + p1]  = wid;
        slotList[e1 * T_TOK + p1] = 2 * wid;
        pairW[2 * wid] = w1;
        int p2 = atomicAdd(&cnt[e2], 1);
        tokList[e2 * T_TOK + p2]  = wid;
        slotList[e2 * T_TOK + p2] = 2 * wid + 1;
        pairW[2 * wid + 1] = w2;
    }
}

// ---------------- fp32 -> bf16 convert ----------------
__global__ __launch_bounds__(256) void convert_kernel(
    const float* __restrict__ src, short* __restrict__ dst, int n4)
{
    int idx = blockIdx.x * 256 + threadIdx.x;
    int stride = gridDim.x * 256;
    for (; idx < n4; idx += stride) {
        floatx4 v = *(const floatx4*)(src + (size_t)idx * 4);
        short4v o = { f2b(v.x), f2b(v.y), f2b(v.z), f2b(v.w) };
        *(short4v*)(dst + (size_t)idx * 4) = o;
    }
}

// ---------------- m97-style 128x128x64 bf16 GEMM with global_load_lds ----------------
// C[scatter[m]][n] = sum_k A[gather[m]][k] * B[n][k]  (all bf16, B K-major)
__global__ __launch_bounds__(256) void gemm128(
    const short* __restrict__ A, const short* __restrict__ B, short* __restrict__ C,
    const int* __restrict__ counts, int fixedM,
    const int* __restrict__ gatherIdx, const int* __restrict__ scatterIdx,
    int N, int K)
{
    const int e = blockIdx.z;
    const int M = counts ? counts[e] : fixedM;
    const int m_base = blockIdx.x * 128;      // x = M-tiles: consecutive blocks share B tile (L2)
    if (m_base >= M) return;
    const int n_base = blockIdx.y * 128;

    __shared__ short As[128 * 64];
    __shared__ short Bs[128 * 64];

    const short* Be = B + (size_t)e * (size_t)N * K;

    const int tid  = threadIdx.x;
    const int w    = tid >> 6;
    const int lane = tid & 63;
    const int quad = lane >> 4;
    const int l16  = lane & 15;
    const int wm = w >> 1, wn = w & 1;

    // staging: wave w stages rows w*32 .. w*32+31 (4 instrs x 8 rows x 16B/lane)
    const short* aSrc[4];
    const short* bSrc[4];
    int ldsOff[4];
#pragma unroll
    for (int i = 0; i < 4; ++i) {
        int r = w * 32 + i * 8 + (lane >> 3);
        int gr = m_base + r;
        int pos = gr < M ? gr : (M - 1);
        int arow = gatherIdx ? gatherIdx[e * T_TOK + pos] : pos;
        aSrc[i] = A + (size_t)arow * K + (lane & 7) * 8;
        bSrc[i] = Be + (size_t)(n_base + r) * K + (lane & 7) * 8;
        ldsOff[i] = (w * 32 + i * 8) * 64;
    }

    floatx4 acc[4][4] = {};

    for (int k0 = 0; k0 < K; k0 += 64) {
#pragma unroll
        for (int i = 0; i < 4; ++i) {
            async16(aSrc[i] + k0, As + ldsOff[i]);
            async16(bSrc[i] + k0, Bs + ldsOff[i]);
        }
        __syncthreads();
        short8 af[4], bf[4];
#pragma unroll
        for (int kk = 0; kk < 64; kk += 32) {
#pragma unroll
            for (int m = 0; m < 4; ++m)
                af[m] = *(const short8*)(As + (wm * 64 + m * 16 + l16) * 64 + kk + quad * 8);
#pragma unroll
            for (int n = 0; n < 4; ++n)
                bf[n] = *(const short8*)(Bs + (wn * 64 + n * 16 + l16) * 64 + kk + quad * 8);
#pragma unroll
            for (int m = 0; m < 4; ++m)
#pragma unroll
                for (int n = 0; n < 4; ++n)
                    acc[m][n] = __builtin_amdgcn_mfma_f32_16x16x32_bf16(af[m], bf[n], acc[m][n], 0, 0, 0);
        }
        __syncthreads();
    }

    // epilogue: C/D layout col=l16, row=quad*4+reg
#pragma unroll
    for (int m = 0; m < 4; ++m) {
#pragma unroll
        for (int r = 0; r < 4; ++r) {
            int row = m_base + wm * 64 + m * 16 + quad * 4 + r;
            if (row >= M) continue;
            int crow = scatterIdx ? scatterIdx[e * T_TOK + row] : row;
#pragma unroll
            for (int n = 0; n < 4; ++n) {
                int col = n_base + wn * 64 + n * 16 + l16;
                C[(size_t)crow * N + col] = f2b(acc[m][n][r]);
            }
        }
    }
}

// ---------------- silu(g)*u elementwise (bf16) ----------------
__global__ __launch_bounds__(256) void silu_mul_kernel(
    const short* __restrict__ g, const short* __restrict__ u,
    short* __restrict__ o, int n8)
{
    int idx = blockIdx.x * 256 + threadIdx.x;
    if (idx >= n8) return;
    short8 gv = *(const short8*)(g + (size_t)idx * 8);
    short8 uv = *(const short8*)(u + (size_t)idx * 8);
    short8 ov;
#pragma unroll
    for (int j = 0; j < 8; ++j) {
        float gf = b2f(gv[j]);
        float uf = b2f(uv[j]);
        ov[j] = f2b(gf / (1.0f + __expf(-gf)) * uf);
    }
    *(short8*)(o + (size_t)idx * 8) = ov;
}

// ---------------- Combine (bf16 intermediates -> fp32 out) ----------------
__global__ __launch_bounds__(256) void combine_kernel(
    const short* __restrict__ outPairs, const short* __restrict__ sharedOut,
    const float* __restrict__ pairW, float* __restrict__ out)
{
    size_t gi = ((size_t)blockIdx.x * 256 + threadIdx.x) * 8;
    int t = (int)(gi >> 11);
    int h = (int)(gi & (H - 1));
    float w0 = pairW[2 * t], w1 = pairW[2 * t + 1];
    short8 p0 = *(const short8*)(outPairs + (size_t)(2 * t) * H + h);
    short8 p1 = *(const short8*)(outPairs + (size_t)(2 * t + 1) * H + h);
    short8 sh = *(const short8*)(sharedOut + gi);
    floatx4 o0, o1;
#pragma unroll
    for (int j = 0; j < 4; ++j)
        o0[j] = w0 * b2f(p0[j]) + w1 * b2f(p1[j]) + b2f(sh[j]);
#pragma unroll
    for (int j = 0; j < 4; ++j)
        o1[j] = w0 * b2f(p0[4 + j]) + w1 * b2f(p1[4 + j]) + b2f(sh[4 + j]);
    *(floatx4*)(out + gi)     = o0;
    *(floatx4*)(out + gi + 4) = o1;
}

// ================= FALLBACK (round-2, fp32-staging 64x64 GEMM) =================
#define LDS_STRIDE 72
template <bool GATEUP, bool A_BF16>
__global__ __launch_bounds__(256) void gemm_tile(
    const void* __restrict__ Av, const float* __restrict__ B1,
    const float* __restrict__ B2, short* __restrict__ C,
    const int* __restrict__ counts, int fixedM,
    const int* __restrict__ gatherIdx, const int* __restrict__ scatterIdx,
    int N, int K)
{
    const int e = blockIdx.z;
    const int M = counts ? counts[e] : fixedM;
    const int m_base = blockIdx.y * 64;
    if (m_base >= M) return;
    const int n_base = blockIdx.x * 64;

    extern __shared__ short lds[];
    short* As  = lds;
    short* Bs1 = lds + 64 * LDS_STRIDE;
    short* Bs2 = GATEUP ? (lds + 2 * 64 * LDS_STRIDE) : nullptr;

    const float* B1e = B1 + (size_t)e * N * K;
    const float* B2e = GATEUP ? (B2 + (size_t)e * N * K) : nullptr;

    const int tid  = threadIdx.x;
    const int wave = tid >> 6;
    const int lane = tid & 63;
    const int quad = lane >> 4;
    const int l16  = lane & 15;

    int asrc[4];
    if (A_BF16) {
#pragma unroll
        for (int i = 0; i < 2; ++i) {
            int r = (tid >> 3) + 32 * i;
            int gr = m_base + r;
            int pos = gr < M ? gr : (M - 1);
            asrc[i] = gatherIdx ? gatherIdx[e * T_TOK + pos] : pos;
        }
    } else {
#pragma unroll
        for (int i = 0; i < 4; ++i) {
            int r = (tid >> 4) + 16 * i;
            int gr = m_base + r;
            int pos = gr < M ? gr : (M - 1);
            asrc[i] = gatherIdx ? gatherIdx[e * T_TOK + pos] : pos;
        }
    }

    floatx4 accg[4] = {};
    floatx4 accu[4] = {};

    const int kIters = K >> 6;
    for (int kt = 0; kt < kIters; ++kt) {
        const int k0 = kt << 6;
        if (A_BF16) {
            const short* A = (const short*)Av;
#pragma unroll
            for (int i = 0; i < 2; ++i) {
                int r = (tid >> 3) + 32 * i;
                int kc = tid & 7;
                short8 av = *(const short8*)(A + (size_t)asrc[i] * K + k0 + kc * 8);
                *(short8*)(As + r * LDS_STRIDE + kc * 8) = av;
            }
        } else {
            const float* A = (const float*)Av;
#pragma unroll
            for (int i = 0; i < 4; ++i) {
                int r = (tid >> 4) + 16 * i;
                int kc = tid & 15;
                floatx4 av = *(const floatx4*)(A + (size_t)asrc[i] * K + k0 + kc * 4);
                short4v cv = { f2b(av.x), f2b(av.y), f2b(av.z), f2b(av.w) };
                *(short4v*)(As + r * LDS_STRIDE + kc * 4) = cv;
            }
        }
#pragma unroll
        for (int i = 0; i < 4; ++i) {
            int r = (tid >> 4) + 16 * i;
            int kc = tid & 15;
            size_t goff = (size_t)(n_base + r) * K + k0 + kc * 4;
            floatx4 b1 = *(const floatx4*)(B1e + goff);
            short4v c1 = { f2b(b1.x), f2b(b1.y), f2b(b1.z), f2b(b1.w) };
            *(short4v*)(Bs1 + r * LDS_STRIDE + kc * 4) = c1;
            if (GATEUP) {
                floatx4 b2 = *(const floatx4*)(B2e + goff);
                short4v c2 = { f2b(b2.x), f2b(b2.y), f2b(b2.z), f2b(b2.w) };
                *(short4v*)(Bs2 + r * LDS_STRIDE + kc * 4) = c2;
            }
        }
        __syncthreads();
#pragma unroll
        for (int kk = 0; kk < 64; kk += 32) {
            short8 af = *(const short8*)(As + (wave * 16 + l16) * LDS_STRIDE + kk + quad * 8);
#pragma unroll
            for (int n = 0; n < 4; ++n) {
                short8 b1 = *(const short8*)(Bs1 + (n * 16 + l16) * LDS_STRIDE + kk + quad * 8);
                accg[n] = __builtin_amdgcn_mfma_f32_16x16x32_bf16(af, b1, accg[n], 0, 0, 0);
                if (GATEUP) {
                    short8 b2 = *(const short8*)(Bs2 + (n * 16 + l16) * LDS_STRIDE + kk + quad * 8);
                    accu[n] = __builtin_amdgcn_mfma_f32_16x16x32_bf16(af, b2, accu[n], 0, 0, 0);
                }
            }
        }
        __syncthreads();
    }

#pragma unroll
    for (int n = 0; n < 4; ++n) {
#pragma unroll
        for (int r = 0; r < 4; ++r) {
            int trow = wave * 16 + quad * 4 + r;
            int grow = m_base + trow;
            if (grow >= M) continue;
            int crow = scatterIdx ? scatterIdx[e * T_TOK + grow] : grow;
            float v;
            if (GATEUP) {
                float g = accg[n][r];
                float u = accu[n][r];
                v = g / (1.0f + __expf(-g)) * u;
            } else {
                v = accg[n][r];
            }
            C[(size_t)crow * N + n_base + n * 16 + l16] = f2b(v);
        }
    }
}

extern "C" void kernel_launch(void* const* d_in, const int* in_sizes, int n_in,
                              void* d_out, int out_size, void* d_ws, size_t ws_size,
                              hipStream_t stream)
{
    const float* x    = (const float*)d_in[0];
    const float* rw   = (const float*)d_in[1];
    const float* bias = (const float*)d_in[2];
    const float* gw   = (const float*)d_in[3];
    const float* uw   = (const float*)d_in[4];
    const float* dw   = (const float*)d_in[5];
    const float* sgw  = (const float*)d_in[6];
    const float* suw  = (const float*)d_in[7];
    const float* sdw  = (const float*)d_in[8];
    float* out = (float*)d_out;

    char* ws = (char*)d_ws;
    size_t off = 0;
    auto alloc = [&](size_t bytes) {
        off = (off + 255) & ~(size_t)255;
        void* p = ws + off;
        off += bytes;
        return p;
    };
    // common
    int*   cnt      = (int*)  alloc(NEXP * sizeof(int));
    int*   tokList  = (int*)  alloc((size_t)NEXP * T_TOK * sizeof(int));
    int*   slotList = (int*)  alloc((size_t)NEXP * T_TOK * sizeof(int));
    float* pairW    = (float*)alloc((size_t)2 * T_TOK * sizeof(float));
    short* hiddenP   = (short*)alloc((size_t)2 * T_TOK * IMOE * sizeof(short));
    short* outPairs  = (short*)alloc((size_t)2 * T_TOK * H * sizeof(short));
    short* hiddenS   = (short*)alloc((size_t)T_TOK * ISH * sizeof(short));
    short* sharedOut = (short*)alloc((size_t)T_TOK * H * sizeof(short));
    size_t off_common = off;
    // fast-path extras
    short* xb    = (short*)alloc((size_t)T_TOK * H * sizeof(short));
    short* gBuf  = (short*)alloc((size_t)2 * T_TOK * IMOE * sizeof(short));  // also shared G (same size)
    short* uBuf  = (short*)alloc((size_t)2 * T_TOK * IMOE * sizeof(short));
    short* arena = (short*)alloc((size_t)NEXP * IMOE * H * sizeof(short));   // 46.1 MB, max weight
    size_t off_fast = off;

    const bool fastOK = (off_fast <= ws_size);

    hipMemsetAsync(cnt, 0, NEXP * sizeof(int), stream);
    router_kernel<<<T_TOK / 4, 256, 0, stream>>>(x, rw, bias, cnt, tokList, slotList, pairW);

    if (fastOK) {
        const int CVT_GRID = 4096;
        // x -> bf16
        convert_kernel<<<CVT_GRID, 256, 0, stream>>>(x, xb, T_TOK * H / 4);

        // ---- routed gate ----
        convert_kernel<<<CVT_GRID, 256, 0, stream>>>(gw, arena, NEXP * IMOE * H / 4);
        {
            dim3 g(T_TOK / 128, IMOE / 128, NEXP);
            gemm128<<<g, 256, 0, stream>>>(xb, arena, gBuf, cnt, 0, tokList, slotList, IMOE, H);
        }
        // ---- routed up ----
        convert_kernel<<<CVT_GRID, 256, 0, stream>>>(uw, arena, NEXP * IMOE * H / 4);
        {
            dim3 g(T_TOK / 128, IMOE / 128, NEXP);
            gemm128<<<g, 256, 0, stream>>>(xb, arena, uBuf, cnt, 0, tokList, slotList, IMOE, H);
        }
        silu_mul_kernel<<<(2 * T_TOK * IMOE / 8 + 255) / 256, 256, 0, stream>>>(
            gBuf, uBuf, hiddenP, 2 * T_TOK * IMOE / 8);
        // ---- routed down ----
        convert_kernel<<<CVT_GRID, 256, 0, stream>>>(dw, arena, NEXP * H * IMOE / 4);
        {
            dim3 g(T_TOK / 128, H / 128, NEXP);
            gemm128<<<g, 256, 0, stream>>>(hiddenP, arena, outPairs, cnt, 0, slotList, slotList, H, IMOE);
        }
        // ---- shared gate ----
        convert_kernel<<<CVT_GRID, 256, 0, stream>>>(sgw, arena, ISH * H / 4);
        {
            dim3 g(T_TOK / 128, ISH / 128, 1);
            gemm128<<<g, 256, 0, stream>>>(xb, arena, gBuf, nullptr, T_TOK, nullptr, nullptr, ISH, H);
        }
        // ---- shared up ----
        convert_kernel<<<CVT_GRID, 256, 0, stream>>>(suw, arena, ISH * H / 4);
        {
            dim3 g(T_TOK / 128, ISH / 128, 1);
            gemm128<<<g, 256, 0, stream>>>(xb, arena, uBuf, nullptr, T_TOK, nullptr, nullptr, ISH, H);
        }
        silu_mul_kernel<<<(T_TOK * ISH / 8 + 255) / 256, 256, 0, stream>>>(
            gBuf, uBuf, hiddenS, T_TOK * ISH / 8);
        // ---- shared down ----
        convert_kernel<<<CVT_GRID, 256, 0, stream>>>(sdw, arena, H * ISH / 4);
        {
            dim3 g(T_TOK / 128, H / 128, 1);
            gemm128<<<g, 256, 0, stream>>>(hiddenS, arena, sharedOut, nullptr, T_TOK, nullptr, nullptr, H, ISH);
        }
    } else {
        (void)off_common;
        const int ldsGU = 3 * 64 * LDS_STRIDE * sizeof(short);
        const int ldsDN = 2 * 64 * LDS_STRIDE * sizeof(short);
        dim3 g1(IMOE / 64, T_TOK / 64, NEXP);
        gemm_tile<true, false><<<g1, 256, ldsGU, stream>>>(x, gw, uw, hiddenP, cnt, 0,
                                                           tokList, slotList, IMOE, H);
        dim3 g2(H / 64, T_TOK / 64, NEXP);
        gemm_tile<false, true><<<g2, 256, ldsDN, stream>>>(hiddenP, dw, nullptr, outPairs, cnt, 0,
                                                           slotList, slotList, H, IMOE);
        dim3 g3(ISH / 64, T_TOK / 64, 1);
        gemm_tile<true, false><<<g3, 256, ldsGU, stream>>>(x, sgw, suw, hiddenS, nullptr, T_TOK,
                                                           nullptr, nullptr, ISH, H);
        dim3 g4(H / 64, T_TOK / 64, 1);
        gemm_tile<false, true><<<g4, 256, ldsDN, stream>>>(hiddenS, sdw, nullptr, sharedOut, nullptr, T_TOK,
                                                           nullptr, nullptr, H, ISH);
    }

    combine_kernel<<<(T_TOK * H / 8) / 256, 256, 0, stream>>>(outPairs, sharedOut, pairW, out);
}

// Round 4
// 700.857 us; speedup vs baseline: 1.7875x; 1.4405x over previous
//
#include <hip/hip_runtime.h>
#include <hip/hip_bf16.h>
#include <math.h>

#define H 2048
#define IMOE 1408
#define NEXP 8
#define T_TOK 2048
#define ISH 2816
#define SCALEF 2.5f

#define NT_GU_R (IMOE / 64)   // 22
#define NT_GU_S (ISH / 64)    // 44
#define NT_DN   (H / 128)     // 16
#define GU_GRID (39 * NT_GU_R + 16 * NT_GU_S)  // 858 + 704 = 1562
#define DN_GRID (39 * NT_DN + 16 * NT_DN)      // 624 + 256 = 880

typedef __attribute__((ext_vector_type(8))) short short8;
typedef __attribute__((ext_vector_type(4))) short short4v;
typedef __attribute__((ext_vector_type(4))) float floatx4;

union U8 { short8 s; unsigned u[4]; };

__device__ inline float b2f(short v) {
    unsigned int u = ((unsigned int)(unsigned short)v) << 16;
    float f; __builtin_memcpy(&f, &u, 4); return f;
}
__device__ inline short f2b(float f) {
    __hip_bfloat16 h = __float2bfloat16(f);
    short s; __builtin_memcpy(&s, &h, 2); return s;
}
__device__ __forceinline__ unsigned pkbf16(float a, float b) {
    float2 t; t.x = a; t.y = b;
    __hip_bfloat162 h2 = __float22bfloat162_rn(t);
    unsigned u; __builtin_memcpy(&u, &h2, 4); return u;
}

// async 16B/lane global->LDS; LDS dest = wave-uniform base + lane*16
__device__ __forceinline__ void async16(const short* g, short* l) {
    __builtin_amdgcn_global_load_lds(
        (const __attribute__((address_space(1))) unsigned*)g,
        (__attribute__((address_space(3))) unsigned*)l, 16, 0, 0);
}

// ---------------- Router (fp32, matches reference exactly) ----------------
__global__ __launch_bounds__(256) void router_kernel(
    const float* __restrict__ x, const float* __restrict__ rw,
    const float* __restrict__ bias,
    int* __restrict__ cnt, int* __restrict__ tokList, int* __restrict__ slotList,
    float* __restrict__ pairW)
{
    const int wid  = (blockIdx.x * 256 + threadIdx.x) >> 6;
    const int lane = threadIdx.x & 63;
    if (wid >= T_TOK) return;
    const float* xr = x + (size_t)wid * H;

    float acc[NEXP];
#pragma unroll
    for (int e = 0; e < NEXP; ++e) acc[e] = 0.f;

#pragma unroll
    for (int c = 0; c < 8; ++c) {
        int idx = (c * 64 + lane) * 4;
        floatx4 xv = *(const floatx4*)(xr + idx);
#pragma unroll
        for (int e = 0; e < NEXP; ++e) {
            floatx4 wv = *(const floatx4*)(rw + e * H + idx);
            acc[e] += xv.x * wv.x + xv.y * wv.y + xv.z * wv.z + xv.w * wv.w;
        }
    }
#pragma unroll
    for (int e = 0; e < NEXP; ++e)
        for (int off = 32; off; off >>= 1)
            acc[e] += __shfl_xor(acc[e], off, 64);

    if (lane == 0) {
        float s[NEXP], sfc[NEXP];
#pragma unroll
        for (int e = 0; e < NEXP; ++e) {
            s[e]   = 1.0f / (1.0f + expf(-acc[e]));
            sfc[e] = s[e] + bias[e];
        }
        float gs[4];
#pragma unroll
        for (int g = 0; g < 4; ++g) gs[g] = sfc[2 * g] + sfc[2 * g + 1];
        int g1 = 0;
        for (int g = 1; g < 4; ++g) if (gs[g] > gs[g1]) g1 = g;
        int g2 = -1;
        for (int g = 0; g < 4; ++g) {
            if (g == g1) continue;
            if (g2 < 0 || gs[g] > gs[g2]) g2 = g;
        }
        float msk[NEXP];
#pragma unroll
        for (int e = 0; e < NEXP; ++e) {
            int g = e >> 1;
            msk[e] = (g == g1 || g == g2) ? sfc[e] : 0.0f;
        }
        int e1 = 0;
        for (int e = 1; e < NEXP; ++e) if (msk[e] > msk[e1]) e1 = e;
        int e2 = -1;
        for (int e = 0; e < NEXP; ++e) {
            if (e == e1) continue;
            if (e2 < 0 || msk[e] > msk[e2]) e2 = e;
        }
        float w1 = s[e1], w2 = s[e2];
        float inv = SCALEF / (w1 + w2 + 1e-20f);
        w1 *= inv; w2 *= inv;
        int p1 = atomicAdd(&cnt[e1], 1);
        tokList[e1 * T_TOK + p1]  = wid;
        slotList[e1 * T_TOK + p1] = 2 * wid;
        pairW[2 * wid] = w1;
        int p2 = atomicAdd(&cnt[e2], 1);
        tokList[e2 * T_TOK + p2]  = wid;
        slotList[e2 * T_TOK + p2] = 2 * wid + 1;
        pairW[2 * wid + 1] = w2;
    }
}

// ---------------- Plan: counts -> compact row bases + tile-item prefix tables ----------------
// meta[0..8]  : M per entry (entry 8 = shared, 2048)
// meta[9..17] : compact row base
// meta[20..29]: gate/up item starts (meta[20]=0 .. meta[29]=total)
// meta[32..41]: down item starts
__global__ void plan_kernel(const int* __restrict__ cnt, int* __restrict__ meta)
{
    if (blockIdx.x != 0 || threadIdx.x != 0) return;
    int base = 0, gu = 0, dn = 0;
    meta[20] = 0; meta[32] = 0;
    for (int e = 0; e < NEXP; ++e) {
        int M = cnt[e];
        meta[e] = M;
        meta[9 + e] = base;
        base += M;
        int MT = (M + 127) >> 7;
        gu += MT * NT_GU_R;
        dn += MT * NT_DN;
        meta[21 + e] = gu;
        meta[33 + e] = dn;
    }
    meta[8]  = T_TOK;   // shared M
    meta[17] = 0;       // shared base (separate buffer)
    meta[29] = gu + 16 * NT_GU_S;
    meta[41] = dn + 16 * NT_DN;
}

// ---------------- fp32 -> bf16 convert (x only) ----------------
__global__ __launch_bounds__(256) void convert_kernel(
    const float* __restrict__ src, short* __restrict__ dst, int n4)
{
    int idx = blockIdx.x * 256 + threadIdx.x;
    int stride = gridDim.x * 256;
    for (; idx < n4; idx += stride) {
        floatx4 v = *(const floatx4*)(src + (size_t)idx * 4);
        short4v o = { f2b(v.x), f2b(v.y), f2b(v.z), f2b(v.w) };
        *(short4v*)(dst + (size_t)idx * 4) = o;
    }
}

// ---------------- Fused gate+up grouped GEMM ----------------
// BM=128 (A rows, gathered bf16 x), BN=64 per matrix, BK=64, K=2048 fixed.
// B (fp32 weights) staged with in-kernel cvt. XOR-swizzled LDS rows.
// Epilogue: silu(g)*u -> compact hidden (bf16).
__global__ __launch_bounds__(256) void gu_gemm(
    const short* __restrict__ xb,
    const float* __restrict__ gw, const float* __restrict__ uw,
    const float* __restrict__ sgw, const float* __restrict__ suw,
    short* __restrict__ hiddenP, short* __restrict__ hiddenS,
    const int* __restrict__ tokList, const int* __restrict__ meta)
{
    const int idx = blockIdx.x;
    if (idx >= meta[29]) return;
    int e = 0;
    while (e < 8 && idx >= meta[21 + e]) ++e;

    int M, NT, Nout, rowBase;
    const float *b1, *b2;
    const int* gat;
    short* outP;
    if (e < 8) {
        M = meta[e]; NT = NT_GU_R; Nout = IMOE; rowBase = meta[9 + e];
        b1 = gw + (size_t)e * IMOE * H;
        b2 = uw + (size_t)e * IMOE * H;
        gat = tokList + e * T_TOK;
        outP = hiddenP;
    } else {
        M = T_TOK; NT = NT_GU_S; Nout = ISH; rowBase = 0;
        b1 = sgw; b2 = suw; gat = nullptr; outP = hiddenS;
    }
    const int MT = (M + 127) >> 7;
    const int local = idx - meta[20 + e];
    const int mt = local % MT;          // mt-minor: adjacent blocks share weight tile
    const int nt = local / MT;

    __shared__ short As[128 * 64];
    __shared__ short Bg[64 * 64];
    __shared__ short Bu[64 * 64];

    const int tid  = threadIdx.x;
    const int w    = tid >> 6;
    const int lane = tid & 63;
    const int quad = lane >> 4;
    const int l16  = lane & 15;
    const int wm = w >> 1, wn = w & 1;

    // A staging (async16, swizzled source chunk)
    const int r8 = lane >> 3;                 // row within 8-row group
    const int cs = (lane & 7) ^ r8;           // source chunk (phys chunk = lane&7)
    const short* aSrc[4];
    short* ldsA[4];
#pragma unroll
    for (int i = 0; i < 4; ++i) {
        int r = w * 32 + i * 8 + r8;
        int p = mt * 128 + r;
        int pos = p < M ? p : (M - 1);
        int arow = gat ? gat[pos] : pos;
        aSrc[i] = xb + (size_t)arow * H + cs * 8;
        ldsA[i] = As + (w * 32 + i * 8) * 64;
    }

    // B staging indices (fp32 -> bf16 cvt path)
    const int br = tid >> 2;                  // 0..63
    const int bj = tid & 3;                   // 16-float col group
    const int bs = br & 7;
    const float* b1p = b1 + (size_t)(nt * 64 + br) * H + bj * 16;
    const float* b2p = b2 + (size_t)(nt * 64 + br) * H + bj * 16;
    short* bgDst0 = Bg + br * 64 + (((2 * bj)    ) ^ bs) * 8;
    short* bgDst1 = Bg + br * 64 + (((2 * bj) + 1) ^ bs) * 8;
    short* buDst0 = Bu + br * 64 + (((2 * bj)    ) ^ bs) * 8;
    short* buDst1 = Bu + br * 64 + (((2 * bj) + 1) ^ bs) * 8;

    floatx4 accg[4][2] = {};
    floatx4 accu[4][2] = {};

    for (int k0 = 0; k0 < H; k0 += 64) {
#pragma unroll
        for (int i = 0; i < 4; ++i)
            async16(aSrc[i] + k0, ldsA[i]);
        {
            floatx4 v0 = ((const floatx4*)(b1p + k0))[0];
            floatx4 v1 = ((const floatx4*)(b1p + k0))[1];
            floatx4 v2 = ((const floatx4*)(b1p + k0))[2];
            floatx4 v3 = ((const floatx4*)(b1p + k0))[3];
            U8 lo, hi;
            lo.u[0] = pkbf16(v0.x, v0.y); lo.u[1] = pkbf16(v0.z, v0.w);
            lo.u[2] = pkbf16(v1.x, v1.y); lo.u[3] = pkbf16(v1.z, v1.w);
            hi.u[0] = pkbf16(v2.x, v2.y); hi.u[1] = pkbf16(v2.z, v2.w);
            hi.u[2] = pkbf16(v3.x, v3.y); hi.u[3] = pkbf16(v3.z, v3.w);
            *(short8*)bgDst0 = lo.s;
            *(short8*)bgDst1 = hi.s;
        }
        {
            floatx4 v0 = ((const floatx4*)(b2p + k0))[0];
            floatx4 v1 = ((const floatx4*)(b2p + k0))[1];
            floatx4 v2 = ((const floatx4*)(b2p + k0))[2];
            floatx4 v3 = ((const floatx4*)(b2p + k0))[3];
            U8 lo, hi;
            lo.u[0] = pkbf16(v0.x, v0.y); lo.u[1] = pkbf16(v0.z, v0.w);
            lo.u[2] = pkbf16(v1.x, v1.y); lo.u[3] = pkbf16(v1.z, v1.w);
            hi.u[0] = pkbf16(v2.x, v2.y); hi.u[1] = pkbf16(v2.z, v2.w);
            hi.u[2] = pkbf16(v3.x, v3.y); hi.u[3] = pkbf16(v3.z, v3.w);
            *(short8*)buDst0 = lo.s;
            *(short8*)buDst1 = hi.s;
        }
        __syncthreads();
        const int sw = l16 & 7;
        short8 af[4], bgf[2], buf[2];
#pragma unroll
        for (int kk2 = 0; kk2 < 2; ++kk2) {
            const int c = kk2 * 4 + quad;
#pragma unroll
            for (int m = 0; m < 4; ++m)
                af[m] = *(const short8*)(As + (wm * 64 + m * 16 + l16) * 64 + (c ^ sw) * 8);
#pragma unroll
            for (int n = 0; n < 2; ++n) {
                bgf[n] = *(const short8*)(Bg + (wn * 32 + n * 16 + l16) * 64 + (c ^ sw) * 8);
                buf[n] = *(const short8*)(Bu + (wn * 32 + n * 16 + l16) * 64 + (c ^ sw) * 8);
            }
#pragma unroll
            for (int m = 0; m < 4; ++m)
#pragma unroll
                for (int n = 0; n < 2; ++n) {
                    accg[m][n] = __builtin_amdgcn_mfma_f32_16x16x32_bf16(af[m], bgf[n], accg[m][n], 0, 0, 0);
                    accu[m][n] = __builtin_amdgcn_mfma_f32_16x16x32_bf16(af[m], buf[n], accu[m][n], 0, 0, 0);
                }
        }
        __syncthreads();
    }

    // epilogue: silu(g)*u -> compact hidden. C/D layout: col=l16, row=quad*4+rr
#pragma unroll
    for (int m = 0; m < 4; ++m) {
#pragma unroll
        for (int rr = 0; rr < 4; ++rr) {
            int lr = wm * 64 + m * 16 + quad * 4 + rr;
            int p = mt * 128 + lr;
            if (p >= M) continue;
            size_t rowoff = (size_t)(rowBase + p) * Nout + nt * 64 + wn * 32;
#pragma unroll
            for (int n = 0; n < 2; ++n) {
                float g = accg[m][n][rr];
                float u = accu[m][n][rr];
                outP[rowoff + n * 16 + l16] = f2b(g / (1.0f + __expf(-g)) * u);
            }
        }
    }
}

// ---------------- Down grouped GEMM ----------------
// BM=128 (compact hidden rows), BN=128, BK=64, K = 1408 (routed) / 2816 (shared).
__global__ __launch_bounds__(256) void dn_gemm(
    const short* __restrict__ hiddenP, const short* __restrict__ hiddenS,
    const float* __restrict__ dw, const float* __restrict__ sdw,
    short* __restrict__ outPairs, short* __restrict__ sharedOut,
    const int* __restrict__ slotList, const int* __restrict__ meta)
{
    const int idx = blockIdx.x;
    if (idx >= meta[41]) return;
    int e = 0;
    while (e < 8 && idx >= meta[33 + e]) ++e;

    int M, K, rowBase;
    const float* bp;
    const short* Abase;
    const int* scat;
    short* outP;
    if (e < 8) {
        M = meta[e]; K = IMOE; rowBase = meta[9 + e];
        bp = dw + (size_t)e * H * IMOE;
        Abase = hiddenP; scat = slotList + e * T_TOK; outP = outPairs;
    } else {
        M = T_TOK; K = ISH; rowBase = 0;
        bp = sdw; Abase = hiddenS; scat = nullptr; outP = sharedOut;
    }
    const int MT = (M + 127) >> 7;
    const int local = idx - meta[32 + e];
    const int mt = local % MT;
    const int nt = local / MT;

    __shared__ short As[128 * 64];
    __shared__ short Bs[128 * 64];

    const int tid  = threadIdx.x;
    const int w    = tid >> 6;
    const int lane = tid & 63;
    const int quad = lane >> 4;
    const int l16  = lane & 15;
    const int wm = w >> 1, wn = w & 1;

    const int r8 = lane >> 3;
    const int cs = (lane & 7) ^ r8;
    const short* aSrc[4];
    short* ldsA[4];
#pragma unroll
    for (int i = 0; i < 4; ++i) {
        int r = w * 32 + i * 8 + r8;
        int p = mt * 128 + r;
        int pos = p < M ? p : (M - 1);
        aSrc[i] = Abase + (size_t)(rowBase + pos) * K + cs * 8;
        ldsA[i] = As + (w * 32 + i * 8) * 64;
    }

    const int br = tid >> 1;                  // 0..127
    const int bh = tid & 1;                   // 32-float half
    const int bs = br & 7;
    const float* bpp = bp + (size_t)(nt * 128 + br) * K + bh * 32;
    short* bDst[4];
#pragma unroll
    for (int i = 0; i < 4; ++i)
        bDst[i] = Bs + br * 64 + ((bh * 4 + i) ^ bs) * 8;

    floatx4 acc[4][4] = {};

    const int kIters = K >> 6;
    for (int kt = 0; kt < kIters; ++kt) {
        const int k0 = kt << 6;
#pragma unroll
        for (int i = 0; i < 4; ++i)
            async16(aSrc[i] + k0, ldsA[i]);
#pragma unroll
        for (int i = 0; i < 4; ++i) {
            floatx4 v0 = ((const floatx4*)(bpp + k0))[2 * i];
            floatx4 v1 = ((const floatx4*)(bpp + k0))[2 * i + 1];
            U8 c;
            c.u[0] = pkbf16(v0.x, v0.y); c.u[1] = pkbf16(v0.z, v0.w);
            c.u[2] = pkbf16(v1.x, v1.y); c.u[3] = pkbf16(v1.z, v1.w);
            *(short8*)bDst[i] = c.s;
        }
        __syncthreads();
        const int sw = l16 & 7;
        short8 af[4], bf[4];
#pragma unroll
        for (int kk2 = 0; kk2 < 2; ++kk2) {
            const int c = kk2 * 4 + quad;
#pragma unroll
            for (int m = 0; m < 4; ++m)
                af[m] = *(const short8*)(As + (wm * 64 + m * 16 + l16) * 64 + (c ^ sw) * 8);
#pragma unroll
            for (int n = 0; n < 4; ++n)
                bf[n] = *(const short8*)(Bs + (wn * 64 + n * 16 + l16) * 64 + (c ^ sw) * 8);
#pragma unroll
            for (int m = 0; m < 4; ++m)
#pragma unroll
                for (int n = 0; n < 4; ++n)
                    acc[m][n] = __builtin_amdgcn_mfma_f32_16x16x32_bf16(af[m], bf[n], acc[m][n], 0, 0, 0);
        }
        __syncthreads();
    }

#pragma unroll
    for (int m = 0; m < 4; ++m) {
#pragma unroll
        for (int rr = 0; rr < 4; ++rr) {
            int lr = wm * 64 + m * 16 + quad * 4 + rr;
            int p = mt * 128 + lr;
            if (p >= M) continue;
            int crow = scat ? scat[p] : p;
            size_t rowoff = (size_t)crow * H + nt * 128 + wn * 64;
#pragma unroll
            for (int n = 0; n < 4; ++n)
                outP[rowoff + n * 16 + l16] = f2b(acc[m][n][rr]);
        }
    }
}

// ---------------- Combine ----------------
__global__ __launch_bounds__(256) void combine_kernel(
    const short* __restrict__ outPairs, const short* __restrict__ sharedOut,
    const float* __restrict__ pairW, float* __restrict__ out)
{
    size_t gi = ((size_t)blockIdx.x * 256 + threadIdx.x) * 8;
    int t = (int)(gi >> 11);
    int h = (int)(gi & (H - 1));
    float w0 = pairW[2 * t], w1 = pairW[2 * t + 1];
    short8 p0 = *(const short8*)(outPairs + (size_t)(2 * t) * H + h);
    short8 p1 = *(const short8*)(outPairs + (size_t)(2 * t + 1) * H + h);
    short8 sh = *(const short8*)(sharedOut + gi);
    floatx4 o0, o1;
#pragma unroll
    for (int j = 0; j < 4; ++j)
        o0[j] = w0 * b2f(p0[j]) + w1 * b2f(p1[j]) + b2f(sh[j]);
#pragma unroll
    for (int j = 0; j < 4; ++j)
        o1[j] = w0 * b2f(p0[4 + j]) + w1 * b2f(p1[4 + j]) + b2f(sh[4 + j]);
    *(floatx4*)(out + gi)     = o0;
    *(floatx4*)(out + gi + 4) = o1;
}

extern "C" void kernel_launch(void* const* d_in, const int* in_sizes, int n_in,
                              void* d_out, int out_size, void* d_ws, size_t ws_size,
                              hipStream_t stream)
{
    const float* x    = (const float*)d_in[0];
    const float* rw   = (const float*)d_in[1];
    const float* bias = (const float*)d_in[2];
    const float* gw   = (const float*)d_in[3];
    const float* uw   = (const float*)d_in[4];
    const float* dw   = (const float*)d_in[5];
    const float* sgw  = (const float*)d_in[6];
    const float* suw  = (const float*)d_in[7];
    const float* sdw  = (const float*)d_in[8];
    float* out = (float*)d_out;

    char* ws = (char*)d_ws;
    size_t off = 0;
    auto alloc = [&](size_t bytes) {
        off = (off + 255) & ~(size_t)255;
        void* p = ws + off;
        off += bytes;
        return p;
    };
    int*   cnt       = (int*)  alloc(NEXP * sizeof(int));
    int*   tokList   = (int*)  alloc((size_t)NEXP * T_TOK * sizeof(int));
    int*   slotList  = (int*)  alloc((size_t)NEXP * T_TOK * sizeof(int));
    float* pairW     = (float*)alloc((size_t)2 * T_TOK * sizeof(float));
    int*   meta      = (int*)  alloc(64 * sizeof(int));
    short* xb        = (short*)alloc((size_t)T_TOK * H * sizeof(short));
    short* hiddenP   = (short*)alloc((size_t)2 * T_TOK * IMOE * sizeof(short));  // compact, 4096 rows
    short* hiddenS   = (short*)alloc((size_t)T_TOK * ISH * sizeof(short));
    short* outPairs  = (short*)alloc((size_t)2 * T_TOK * H * sizeof(short));
    short* sharedOut = (short*)alloc((size_t)T_TOK * H * sizeof(short));
    (void)ws_size;

    hipMemsetAsync(cnt, 0, NEXP * sizeof(int), stream);

    router_kernel<<<T_TOK / 4, 256, 0, stream>>>(x, rw, bias, cnt, tokList, slotList, pairW);
    plan_kernel<<<1, 64, 0, stream>>>(cnt, meta);
    convert_kernel<<<2048, 256, 0, stream>>>(x, xb, T_TOK * H / 4);

    gu_gemm<<<GU_GRID, 256, 0, stream>>>(xb, gw, uw, sgw, suw,
                                         hiddenP, hiddenS, tokList, meta);
    dn_gemm<<<DN_GRID, 256, 0, stream>>>(hiddenP, hiddenS, dw, sdw,
                                         outPairs, sharedOut, slotList, meta);

    combine_kernel<<<(T_TOK * H / 8) / 256, 256, 0, stream>>>(outPairs, sharedOut, pairW, out);
}